// Round 18
// baseline (463.906 us; speedup 1.0000x reference)
//
#include <hip/hip_runtime.h>

// CSR-bucket pipeline (no global float atomics):
//   memset(deg) ; deg_cast (deg hist + x->fp16) ; scan_partial ; scan_final ;
//   fill_a (bucket edges) ; fill_gather (csr scatter + GCN1 LDS-accumulate + agg) ;
//   h1 ; w1tab ; edge_mlp (fp16 MFMA + fused GCN2 node matmul) ;
//   gcn2_bucket (edge-parallel GCN2 aggregate + output)

typedef __attribute__((ext_vector_type(8))) short short8;
typedef __attribute__((ext_vector_type(4))) float f32x4;
typedef __attribute__((ext_vector_type(8))) _Float16 f16x8;
typedef __attribute__((ext_vector_type(4))) _Float16 f16x4;
typedef __attribute__((ext_vector_type(2))) _Float16 f16x2;

#define SCAN_CHUNK 2048   // elements per scan block (256 thr x 8)
#define FILL_CH 4096      // edges per phase-A block (256 thr x 16)

__device__ __forceinline__ unsigned short f2bf(float x) {   // RNE f32->bf16 (cold paths only)
    unsigned int u = __float_as_uint(x);
    return (unsigned short)((u + 0x7FFFu + ((u >> 16) & 1u)) >> 16);
}
__device__ __forceinline__ float bf2f(unsigned short h) {
    return __uint_as_float(((unsigned int)h) << 16);
}
// cheap truncation split: u ~= hi + lo with |err| ~ 2^-16 |u|
__device__ __forceinline__ void splitT(float u, short& hi, short& lo) {
    unsigned int ub = __float_as_uint(u);
    hi = (short)(ub >> 16);
    float r = u - __uint_as_float(ub & 0xFFFF0000u);
    lo = (short)(__float_as_uint(r) >> 16);
}
__device__ __forceinline__ f16x8 relu8(f16x8 v) {
    f16x8 z = {0, 0, 0, 0, 0, 0, 0, 0};
#if __has_builtin(__builtin_elementwise_max)
    return __builtin_elementwise_max(v, z);
#else
    f16x8 o;
#pragma unroll
    for (int j = 0; j < 8; ++j) o[j] = v[j] > (_Float16)0 ? v[j] : (_Float16)0;
    return o;
#endif
}

// fused: degree histogram + x -> fp16 cast
__global__ void k_deg_cast(const int* __restrict__ col, int* __restrict__ deg,
                           const float4* __restrict__ x4, f16x4* __restrict__ xh4,
                           int E, int m4) {
    int e = blockIdx.x * blockDim.x + threadIdx.x;
    if (e < m4) {
        float4 v = x4[e];
        f16x4 o;
        o[0] = (_Float16)v.x; o[1] = (_Float16)v.y;
        o[2] = (_Float16)v.z; o[3] = (_Float16)v.w;
        xh4[e] = o;
    }
    if (e < E) atomicAdd(&deg[col[e]], 1);
}

__global__ __launch_bounds__(256) void k_scan_partial(const int* __restrict__ deg,
                                                      int* __restrict__ part, int n) {
    __shared__ int wtot[4];
    int tid = threadIdx.x;
    int base = blockIdx.x * SCAN_CHUNK + tid * 8;
    int s = 0;
#pragma unroll
    for (int i = 0; i < 8; ++i) { int idx = base + i; if (idx < n) s += deg[idx]; }
    for (int off = 1; off < 64; off <<= 1) s += __shfl_xor(s, off);
    if ((tid & 63) == 0) wtot[tid >> 6] = s;
    __syncthreads();
    if (tid == 0) part[blockIdx.x] = wtot[0] + wtot[1] + wtot[2] + wtot[3];
}

// merged: per-block offset from partials (wave 0, in-register) + block-local
// exclusive scan + ptr + bcur + dinv
__global__ __launch_bounds__(256) void k_scan_final(const int* __restrict__ deg,
                                                    const int* __restrict__ part,
                                                    int* __restrict__ ptr,
                                                    int* __restrict__ bcur,
                                                    float* __restrict__ dinv,
                                                    int n, int nb, int E) {
    __shared__ int wtot[4];
    __shared__ int offsS;
    int tid = threadIdx.x;
    int lane = tid & 63, wv = tid >> 6;
    if (wv == 0) {                          // re-scan <=64 partials, keep ours
        int p = (lane < nb) ? part[lane] : 0;
        int s = p;
        for (int off = 1; off < 64; off <<= 1) {
            int t = __shfl_up(s, off, 64);
            if (lane >= off) s += t;
        }
        if (lane == (int)blockIdx.x) offsS = s - p;   // exclusive
        if (blockIdx.x == 0 && lane == 0) ptr[n] = E;
    }
    int base = blockIdx.x * SCAN_CHUNK + tid * 8;
    int d[8];
    int t8 = 0;
#pragma unroll
    for (int i = 0; i < 8; ++i) {
        int idx = base + i;
        d[i] = (idx < n) ? deg[idx] : 0;
        t8 += d[i];
    }
    int s = t8;
    for (int off = 1; off < 64; off <<= 1) {
        int t = __shfl_up(s, off, 64);
        if (lane >= off) s += t;
    }
    if (lane == 63) wtot[wv] = s;
    __syncthreads();
    int wpre = 0;
    for (int w = 0; w < 4; ++w) if (w < wv) wpre += wtot[w];
    int run = offsS + wpre + (s - t8);
#pragma unroll
    for (int i = 0; i < 8; ++i) {
        int idx = base + i;
        if (idx < n) {
            ptr[idx] = run;
            if ((idx & 127) == 0) bcur[idx >> 7] = run;   // bucket staging base
            dinv[idx] = rsqrtf((float)(d[i] + 1));        // +1 self loop
            run += d[i];
        }
    }
}

// fill phase A: bucket edges (128 cols/bucket) into contiguous per-bucket runs
__global__ __launch_bounds__(256) void k_fill_a(const int* __restrict__ row,
                                                const int* __restrict__ col,
                                                int* __restrict__ bcur,
                                                int2* __restrict__ stage, int E, int nb) {
    __shared__ int cnt[512];
    __shared__ int base[512];
    int tid = threadIdx.x;
    int e0 = blockIdx.x * FILL_CH;
    for (int i = tid; i < nb; i += 256) cnt[i] = 0;
    __syncthreads();
    int r[16], c[16];
#pragma unroll
    for (int i = 0; i < 16; ++i) {
        int e = e0 + tid + i * 256;
        if (e < E) {
            r[i] = row[e]; c[i] = col[e];
            atomicAdd(&cnt[c[i] >> 7], 1);
        } else c[i] = -1;
    }
    __syncthreads();
    for (int i = tid; i < nb; i += 256)
        base[i] = cnt[i] ? atomicAdd(&bcur[i], cnt[i]) : 0;
    __syncthreads();
    for (int i = tid; i < nb; i += 256) cnt[i] = 0;
    __syncthreads();
#pragma unroll
    for (int i = 0; i < 16; ++i) {
        if (c[i] >= 0) {
            int b = c[i] >> 7;
            int lp = atomicAdd(&cnt[b], 1);
            stage[base[b] + lp] = make_int2(r[i], c[i]);
        }
    }
}

// fused fill phase B + GCN1 gather: one block per bucket; scatter csr via LDS
// cursors AND accumulate dinv[r]*xh[r] into padded LDS agg; epilogue adds the
// self term and writes agg (fp32). Edge-parallel: no per-node chains.
__global__ __launch_bounds__(256) void k_fill_gather(
        const int* __restrict__ ptr, const int2* __restrict__ stage,
        int* __restrict__ csr, const _Float16* __restrict__ xh,
        const float* __restrict__ x, const float* __restrict__ dinv,
        float* __restrict__ agg, int n) {
    __shared__ int lcur[128];
    __shared__ float aggS[128 * 33];   // pad 32->33 to spread banks
    int b = blockIdx.x;
    int tid = threadIdx.x;
    int c0 = b << 7;
    for (int i = tid; i < 128 * 33; i += 256) aggS[i] = 0.f;
    for (int j = tid; j < 128; j += 256) {
        int idx = c0 + j; if (idx > n) idx = n;
        lcur[j] = ptr[idx];
    }
    __syncthreads();
    int start = ptr[c0];
    int endi = c0 + 128; if (endi > n) endi = n;
    int end = ptr[endi];

    int f4 = tid & 7, es = tid >> 3;   // 32 edge slots x 8 feature slices
    const f16x4* xh4 = (const f16x4*)xh;
    for (int p = start + es; p < end; p += 32) {
        int2 rc = stage[p];
        int r = rc.x, cc = rc.y & 127;
        if (f4 == 0) {                      // csr scatter (one slice does it)
            int pos = atomicAdd(&lcur[cc], 1);
            csr[pos] = r;
        }
        float dr = dinv[r];
        f16x4 xv = xh4[(size_t)r * 8 + f4];
        float* dst = aggS + cc * 33 + f4 * 4;
        atomicAdd(dst + 0, dr * (float)xv[0]);
        atomicAdd(dst + 1, dr * (float)xv[1]);
        atomicAdd(dst + 2, dr * (float)xv[2]);
        atomicAdd(dst + 3, dr * (float)xv[3]);
    }
    __syncthreads();
    // epilogue: agg[v] = dv*sum + dv^2*x[v]
    for (int i = tid; i < 4096; i += 256) {
        int j = i >> 5, f = i & 31;
        int v = c0 + j;
        if (v < n) {
            float dv = dinv[v];
            agg[(size_t)v * 32 + f] = dv * aggS[j * 33 + f] + dv * dv * x[(size_t)v * 32 + f];
        }
    }
}

// dense MFMA: h1 = tanh(agg @ Wg1 + gb), tiles of 16 nodes, one wave/tile
__global__ __launch_bounds__(256) void k_h1(
        const float* __restrict__ agg, const float* __restrict__ gw,
        const float* __restrict__ gb, float* __restrict__ h1, int ntiles) {
    int wid = blockIdx.x * 4 + (threadIdx.x >> 6);
    if (wid >= ntiles) return;
    int lane = threadIdx.x & 63;
    int n16 = lane & 15, q = lane >> 4;

    short8 bh[4], bl[4];
    float bias[4];
#pragma unroll
    for (int t = 0; t < 4; ++t) {
        bias[t] = gb[t * 16 + n16];
        short8 hh, ll;
#pragma unroll
        for (int j = 0; j < 8; ++j) {
            float w = gw[(q * 8 + j) * 64 + t * 16 + n16];
            unsigned short wh = f2bf(w);
            hh[j] = (short)wh;
            ll[j] = (short)f2bf(w - bf2f(wh));
        }
        bh[t] = hh; bl[t] = ll;
    }

    int v0 = wid * 16;
    const float4* a4 = (const float4*)(agg + (size_t)(v0 + n16) * 32);
    float4 A0 = a4[2 * q], A1 = a4[2 * q + 1];
    float a[8] = {A0.x, A0.y, A0.z, A0.w, A1.x, A1.y, A1.z, A1.w};
    short8 ah, al;
#pragma unroll
    for (int j = 0; j < 8; ++j) { short h, l; splitT(a[j], h, l); ah[j] = h; al[j] = l; }

#pragma unroll
    for (int t = 0; t < 4; ++t) {
        f32x4 acc = (f32x4){bias[t], bias[t], bias[t], bias[t]};
        acc = __builtin_amdgcn_mfma_f32_16x16x32_bf16(ah, bh[t], acc, 0, 0, 0);
        acc = __builtin_amdgcn_mfma_f32_16x16x32_bf16(al, bh[t], acc, 0, 0, 0);
        acc = __builtin_amdgcn_mfma_f32_16x16x32_bf16(ah, bl[t], acc, 0, 0, 0);
#pragma unroll
        for (int i = 0; i < 4; ++i)
            h1[(size_t)(v0 + q * 4 + i) * 64 + t * 16 + n16] = tanhf(acc[i]);
    }
}

// dense MFMA (bf16 3-term ~fp32 internally): atab = h1@(W1a-W1b)+b1 ; btab = h1@W1b
// outputs stored as FP16 (RNE) for the fp16 edge MLP
__global__ __launch_bounds__(256, 1) void k_w1tab(
        const float* __restrict__ h1, const float* __restrict__ w1,
        const float* __restrict__ b1,
        _Float16* __restrict__ atab, _Float16* __restrict__ btab, int ntiles) {
    int lane = threadIdx.x & 63;
    int n16 = lane & 15, q = lane >> 4;

    short8 th[4][2], tl[4][2], uh[4][2], ul[4][2];   // wt=W1a-W1b, wb=W1b frags
    float bias[4];
#pragma unroll
    for (int t = 0; t < 4; ++t) {
        bias[t] = b1[t * 16 + n16];
#pragma unroll
        for (int ck = 0; ck < 2; ++ck) {
            short8 h1v, l1v, h2v, l2v;
#pragma unroll
            for (int j = 0; j < 8; ++j) {
                int d = ck * 32 + q * 8 + j;
                float wbv = w1[(64 + d) * 64 + t * 16 + n16];
                float wtv = w1[d * 64 + t * 16 + n16] - wbv;
                unsigned short x1 = f2bf(wtv);
                h1v[j] = (short)x1; l1v[j] = (short)f2bf(wtv - bf2f(x1));
                unsigned short x2 = f2bf(wbv);
                h2v[j] = (short)x2; l2v[j] = (short)f2bf(wbv - bf2f(x2));
            }
            th[t][ck] = h1v; tl[t][ck] = l1v;
            uh[t][ck] = h2v; ul[t][ck] = l2v;
        }
    }

    int nwaves = gridDim.x * 4;
    int wid = blockIdx.x * 4 + (threadIdx.x >> 6);
    for (int tile = wid; tile < ntiles; tile += nwaves) {
        int v0 = tile * 16;
        const float4* a4 = (const float4*)(h1 + (size_t)(v0 + n16) * 64);
        float4 A0 = a4[2 * q], A1 = a4[2 * q + 1];
        float4 A2 = a4[8 + 2 * q], A3 = a4[8 + 2 * q + 1];
        float a[16] = {A0.x, A0.y, A0.z, A0.w, A1.x, A1.y, A1.z, A1.w,
                       A2.x, A2.y, A2.z, A2.w, A3.x, A3.y, A3.z, A3.w};
        short8 ah0, ah1, al0, al1;
#pragma unroll
        for (int j = 0; j < 8; ++j) {
            short h, l;
            splitT(a[j], h, l);      ah0[j] = h; al0[j] = l;
            splitT(a[8 + j], h, l);  ah1[j] = h; al1[j] = l;
        }
#pragma unroll
        for (int t = 0; t < 4; ++t) {
            f32x4 aa = (f32x4){bias[t], bias[t], bias[t], bias[t]};
            aa = __builtin_amdgcn_mfma_f32_16x16x32_bf16(ah0, th[t][0], aa, 0, 0, 0);
            aa = __builtin_amdgcn_mfma_f32_16x16x32_bf16(ah1, th[t][1], aa, 0, 0, 0);
            aa = __builtin_amdgcn_mfma_f32_16x16x32_bf16(al0, th[t][0], aa, 0, 0, 0);
            aa = __builtin_amdgcn_mfma_f32_16x16x32_bf16(al1, th[t][1], aa, 0, 0, 0);
            aa = __builtin_amdgcn_mfma_f32_16x16x32_bf16(ah0, tl[t][0], aa, 0, 0, 0);
            aa = __builtin_amdgcn_mfma_f32_16x16x32_bf16(ah1, tl[t][1], aa, 0, 0, 0);
            f32x4 bb = (f32x4){0.f, 0.f, 0.f, 0.f};
            bb = __builtin_amdgcn_mfma_f32_16x16x32_bf16(ah0, uh[t][0], bb, 0, 0, 0);
            bb = __builtin_amdgcn_mfma_f32_16x16x32_bf16(ah1, uh[t][1], bb, 0, 0, 0);
            bb = __builtin_amdgcn_mfma_f32_16x16x32_bf16(al0, uh[t][0], bb, 0, 0, 0);
            bb = __builtin_amdgcn_mfma_f32_16x16x32_bf16(al1, uh[t][1], bb, 0, 0, 0);
            bb = __builtin_amdgcn_mfma_f32_16x16x32_bf16(ah0, ul[t][0], bb, 0, 0, 0);
            bb = __builtin_amdgcn_mfma_f32_16x16x32_bf16(ah1, ul[t][1], bb, 0, 0, 0);
#pragma unroll
            for (int i = 0; i < 4; ++i) {
                size_t off = (size_t)(v0 + q * 4 + i) * 64 + t * 16 + n16;
                atab[off] = (_Float16)aa[i];
                btab[off] = (_Float16)bb[i];
            }
        }
    }
}

// persistent waves; simple tile loop; fp16 MFMA (fp32 acc); fused GCN2 node
// matmul in epilogue; h2 stored fp16; no atomics
__global__ __launch_bounds__(256) void k_edge_mlp(
        const int* __restrict__ ptr, const int* __restrict__ csr_row,
        const _Float16* __restrict__ atab, const _Float16* __restrict__ btab,
        const float* __restrict__ w2, const float* __restrict__ b2,
        const float* __restrict__ wg, _Float16* __restrict__ h2h, int n) {
    int lane = threadIdx.x & 63;
    int n16 = lane & 15, q = lane >> 4;

    f16x8 wh[4][2];
    float bias[4];
    float wgf[4][4];    // Wg2 rows {t*16+n16}, cols {q*4+jj}
#pragma unroll
    for (int t = 0; t < 4; ++t) {
        bias[t] = b2[t * 16 + n16];
#pragma unroll
        for (int jj = 0; jj < 4; ++jj)
            wgf[t][jj] = wg[(t * 16 + n16) * 16 + q * 4 + jj];
#pragma unroll
        for (int ck = 0; ck < 2; ++ck) {
            f16x8 hh;
#pragma unroll
            for (int j = 0; j < 8; ++j)
                hh[j] = (_Float16)w2[(ck * 32 + q * 8 + j) * 64 + t * 16 + n16];
            wh[t][ck] = hh;
        }
    }

    int nwaves = gridDim.x * 4;
    int wid = blockIdx.x * 4 + (threadIdx.x >> 6);

    for (int c = wid; c < n; c += nwaves) {
        int st = ptr[c], ed = ptr[c + 1];
        const f16x8* a8 = (const f16x8*)(atab + (size_t)c * 64);
        f16x8 A0 = a8[q], A1 = a8[4 + q];
        float red[4] = {0.f, 0.f, 0.f, 0.f};   // init 0 folds relu + empty-segment-0

        int p0 = st;
        int nfull = (ed - st) >> 4;
        for (int ft = 0; ft < nfull; ++ft, p0 += 16) {
            int r = csr_row[p0 + n16];
            const f16x8* b8 = (const f16x8*)(btab + (size_t)r * 64);
            f16x8 u0 = relu8(A0 + b8[q]);
            f16x8 u1 = relu8(A1 + b8[4 + q]);
#pragma unroll
            for (int t = 0; t < 4; ++t) {
                f32x4 acc = (f32x4){bias[t], bias[t], bias[t], bias[t]};
                acc = __builtin_amdgcn_mfma_f32_16x16x32_f16(u0, wh[t][0], acc, 0, 0, 0);
                acc = __builtin_amdgcn_mfma_f32_16x16x32_f16(u1, wh[t][1], acc, 0, 0, 0);
                red[t] = fmaxf(red[t], fmaxf(fmaxf(acc[0], acc[1]), fmaxf(acc[2], acc[3])));
            }
        }
        int rem = ed - p0;
        if (rem > 0) {
            f16x8 u0 = {0, 0, 0, 0, 0, 0, 0, 0};
            f16x8 u1 = {0, 0, 0, 0, 0, 0, 0, 0};
            if (n16 < rem) {
                int r = csr_row[p0 + n16];
                const f16x8* b8 = (const f16x8*)(btab + (size_t)r * 64);
                u0 = relu8(A0 + b8[q]);
                u1 = relu8(A1 + b8[4 + q]);
            }
#pragma unroll
            for (int t = 0; t < 4; ++t) {
                f32x4 acc = (f32x4){bias[t], bias[t], bias[t], bias[t]};
                acc = __builtin_amdgcn_mfma_f32_16x16x32_f16(u0, wh[t][0], acc, 0, 0, 0);
                acc = __builtin_amdgcn_mfma_f32_16x16x32_f16(u1, wh[t][1], acc, 0, 0, 0);
#pragma unroll
                for (int i = 0; i < 4; ++i)
                    if (q * 4 + i < rem) red[t] = fmaxf(red[t], acc[i]);
            }
        }
        // butterfly: all lanes get final segment-max for features t*16+n16
#pragma unroll
        for (int t = 0; t < 4; ++t) {
            red[t] = fmaxf(red[t], __shfl_xor(red[t], 16));
            red[t] = fmaxf(red[t], __shfl_xor(red[t], 32));
        }
        // fused GCN2 node matmul: h2[c][q*4+jj] = sum_d hmax[d]*wg[d][q*4+jj]
        float part[4];
#pragma unroll
        for (int jj = 0; jj < 4; ++jj) {
            part[jj] = red[0] * wgf[0][jj];
            part[jj] = fmaf(red[1], wgf[1][jj], part[jj]);
            part[jj] = fmaf(red[2], wgf[2][jj], part[jj]);
            part[jj] = fmaf(red[3], wgf[3][jj], part[jj]);
        }
#pragma unroll
        for (int off = 1; off < 16; off <<= 1)
#pragma unroll
            for (int jj = 0; jj < 4; ++jj)
                part[jj] += __shfl_xor(part[jj], off);
        if (n16 == 0) {
            f16x4 ph;
            ph[0] = (_Float16)part[0]; ph[1] = (_Float16)part[1];
            ph[2] = (_Float16)part[2]; ph[3] = (_Float16)part[3];
            ((f16x4*)(h2h + (size_t)c * 16))[q] = ph;
        }
    }
}

// edge-parallel GCN2 aggregate per bucket + output write; no per-node chains
__global__ __launch_bounds__(256) void k_gcn2_bucket(
        const int* __restrict__ ptr, const int2* __restrict__ stage,
        const _Float16* __restrict__ h2h, const float* __restrict__ dinv,
        const float* __restrict__ bg, float* __restrict__ out, int n) {
    __shared__ float accS[128 * 17];   // pad 16->17
    int b = blockIdx.x;
    int tid = threadIdx.x;
    int c0 = b << 7;
    for (int i = tid; i < 128 * 17; i += 256) accS[i] = 0.f;
    __syncthreads();
    int start = ptr[c0];
    int endi = c0 + 128; if (endi > n) endi = n;
    int end = ptr[endi];

    int f2 = tid & 7, es = tid >> 3;   // 32 edge slots x 8 slices (2 feats each)
    const f16x2* h22 = (const f16x2*)h2h;
    for (int p = start + es; p < end; p += 32) {
        int2 rc = stage[p];
        int r = rc.x, cc = rc.y & 127;
        float dr = dinv[r];
        f16x2 hv = h22[(size_t)r * 8 + f2];
        float* dst = accS + cc * 17 + f2 * 2;
        atomicAdd(dst + 0, dr * (float)hv[0]);
        atomicAdd(dst + 1, dr * (float)hv[1]);
    }
    __syncthreads();
    for (int i = tid; i < 2048; i += 256) {
        int j = i >> 4, f = i & 15;
        int v = c0 + j;
        if (v < n) {
            float dv = dinv[v];
            float h2s = (float)h2h[(size_t)v * 16 + f];
            out[(size_t)v * 16 + f] = bg[f] + dv * (dv * h2s + accS[j * 17 + f]);
        }
    }
}

extern "C" void kernel_launch(void* const* d_in, const int* in_sizes, int n_in,
                              void* d_out, int out_size, void* d_ws, size_t ws_size,
                              hipStream_t stream) {
    const float* x   = (const float*)d_in[0];
    const int*   ei  = (const int*)d_in[1];
    const float* g1w = (const float*)d_in[2];
    const float* g1b = (const float*)d_in[3];
    const float* ew1 = (const float*)d_in[4];
    const float* eb1 = (const float*)d_in[5];
    const float* ew2 = (const float*)d_in[6];
    const float* eb2 = (const float*)d_in[7];
    const float* g2w = (const float*)d_in[8];
    const float* g2b = (const float*)d_in[9];
    float* out = (float*)d_out;
    float* ws  = (float*)d_ws;

    const int n = in_sizes[0] / 32;      // 50000
    const int E = in_sizes[1] / 2;       // 800000
    const int* row = ei;
    const int* col = ei + E;
    const int ntiles = (n + 15) / 16;    // 3125
    const int nbuck = (n + 127) >> 7;    // 391 buckets of 128 cols

    size_t npad    = ((size_t)n + 63) & ~(size_t)63;
    size_t o_deg   = 0;
    size_t o_ptr   = npad;                      // n+1 (+pad)
    size_t o_csr   = o_ptr + npad + 64;         // E ints
    size_t o_dinv  = o_csr + (size_t)E;
    size_t o_h1    = o_dinv + npad;             // n*64 fp32
    size_t o_atab  = o_h1 + (size_t)n * 64;     // n*64 fp16 = n*32 floats
    size_t o_btab  = o_atab + (size_t)n * 32;   // n*64 fp16
    size_t o_agg   = o_btab + (size_t)n * 32;   // n*32 fp32
    size_t o_xh    = o_agg + (size_t)n * 32;    // n*32 fp16 = n*16 floats
    size_t o_h2h   = o_xh + (size_t)n * 16;     // n*16 fp16 = n*8 floats
    size_t o_stage = o_h2h + (size_t)n * 8;     // E int2 (8B aligned: offsets even)
    size_t o_bcur  = o_stage + (size_t)E * 2;   // nbuck ints
    size_t o_part  = o_bcur + 512;              // 64 ints

    int*      deg    = (int*)(ws + o_deg);
    int*      ptr    = (int*)(ws + o_ptr);
    int*      csr    = (int*)(ws + o_csr);
    float*    dinv   = ws + o_dinv;
    float*    h1     = ws + o_h1;
    _Float16* atab   = (_Float16*)(ws + o_atab);
    _Float16* btab   = (_Float16*)(ws + o_btab);
    float*    agg    = ws + o_agg;
    _Float16* xh     = (_Float16*)(ws + o_xh);
    _Float16* h2h    = (_Float16*)(ws + o_h2h);
    int2*     stage  = (int2*)(ws + o_stage);
    int*      bcur   = (int*)(ws + o_bcur);
    int*      part   = (int*)(ws + o_part);

    int tblk = (ntiles + 3) / 4;
    int scan_nb = (n + SCAN_CHUNK - 1) / SCAN_CHUNK;   // 25 <= 64
    int fill_nb = (E + FILL_CH - 1) / FILL_CH;         // 196
    int m4 = n * 8;                                    // x float4 count

    hipMemsetAsync(deg, 0, npad * sizeof(int), stream);
    k_deg_cast<<<(E + 255) / 256, 256, 0, stream>>>(col, deg, (const float4*)x,
                                                    (f16x4*)xh, E, m4);
    k_scan_partial<<<scan_nb, 256, 0, stream>>>(deg, part, n);
    k_scan_final<<<scan_nb, 256, 0, stream>>>(deg, part, ptr, bcur, dinv, n, scan_nb, E);
    k_fill_a<<<fill_nb, 256, 0, stream>>>(row, col, bcur, stage, E, nbuck);
    k_fill_gather<<<nbuck, 256, 0, stream>>>(ptr, stage, csr, xh, x, dinv, agg, n);
    k_h1<<<tblk, 256, 0, stream>>>(agg, g1w, g1b, h1, ntiles);
    k_w1tab<<<256, 256, 0, stream>>>(h1, ew1, eb1, atab, btab, ntiles);
    k_edge_mlp<<<2048, 256, 0, stream>>>(ptr, csr, atab, btab, ew2, eb2, g2w, h2h, n);
    k_gcn2_bucket<<<nbuck, 256, 0, stream>>>(ptr, stage, h2h, dinv, g2b, out, n);
}

// Round 19
// 235.357 us; speedup vs baseline: 1.9711x; 1.9711x over previous
//
#include <hip/hip_runtime.h>

// CSR-gather pipeline (no float atomics), 10 stream nodes:
//   memset(deg) ; deg_cast (deg hist + x->fp16) ; scan_partial ; scan_final(merged
//   offsets + ptr/dinv/bcur) ; fill_a ; fill_b (bucketed CSR) ; gather32 ; h1 ;
//   w1tab ; edge_mlp (fp16 MFMA + fused GCN2 node matmul) ; gcn2_gather

typedef __attribute__((ext_vector_type(8))) short short8;
typedef __attribute__((ext_vector_type(4))) float f32x4;
typedef __attribute__((ext_vector_type(8))) _Float16 f16x8;
typedef __attribute__((ext_vector_type(4))) _Float16 f16x4;
typedef __attribute__((ext_vector_type(2))) _Float16 f16x2;

#define SCAN_CHUNK 2048   // elements per scan block (256 thr x 8)
#define FILL_CH 4096      // edges per phase-A block (256 thr x 16)

__device__ __forceinline__ unsigned short f2bf(float x) {   // RNE f32->bf16 (cold paths only)
    unsigned int u = __float_as_uint(x);
    return (unsigned short)((u + 0x7FFFu + ((u >> 16) & 1u)) >> 16);
}
__device__ __forceinline__ float bf2f(unsigned short h) {
    return __uint_as_float(((unsigned int)h) << 16);
}
// cheap truncation split: u ~= hi + lo with |err| ~ 2^-16 |u|
__device__ __forceinline__ void splitT(float u, short& hi, short& lo) {
    unsigned int ub = __float_as_uint(u);
    hi = (short)(ub >> 16);
    float r = u - __uint_as_float(ub & 0xFFFF0000u);
    lo = (short)(__float_as_uint(r) >> 16);
}
__device__ __forceinline__ f16x8 relu8(f16x8 v) {
    f16x8 z = {0, 0, 0, 0, 0, 0, 0, 0};
#if __has_builtin(__builtin_elementwise_max)
    return __builtin_elementwise_max(v, z);
#else
    f16x8 o;
#pragma unroll
    for (int j = 0; j < 8; ++j) o[j] = v[j] > (_Float16)0 ? v[j] : (_Float16)0;
    return o;
#endif
}

// fused: degree histogram + x -> fp16 cast
__global__ void k_deg_cast(const int* __restrict__ col, int* __restrict__ deg,
                           const float4* __restrict__ x4, f16x4* __restrict__ xh4,
                           int E, int m4) {
    int e = blockIdx.x * blockDim.x + threadIdx.x;
    if (e < m4) {
        float4 v = x4[e];
        f16x4 o;
        o[0] = (_Float16)v.x; o[1] = (_Float16)v.y;
        o[2] = (_Float16)v.z; o[3] = (_Float16)v.w;
        xh4[e] = o;
    }
    if (e < E) atomicAdd(&deg[col[e]], 1);
}

__global__ __launch_bounds__(256) void k_scan_partial(const int* __restrict__ deg,
                                                      int* __restrict__ part, int n) {
    __shared__ int wtot[4];
    int tid = threadIdx.x;
    int base = blockIdx.x * SCAN_CHUNK + tid * 8;
    int s = 0;
#pragma unroll
    for (int i = 0; i < 8; ++i) { int idx = base + i; if (idx < n) s += deg[idx]; }
    for (int off = 1; off < 64; off <<= 1) s += __shfl_xor(s, off);
    if ((tid & 63) == 0) wtot[tid >> 6] = s;
    __syncthreads();
    if (tid == 0) part[blockIdx.x] = wtot[0] + wtot[1] + wtot[2] + wtot[3];
}

// merged: per-block offset from partials (wave 0, in-register) + block-local
// exclusive scan + ptr + bcur + dinv
__global__ __launch_bounds__(256) void k_scan_final(const int* __restrict__ deg,
                                                    const int* __restrict__ part,
                                                    int* __restrict__ ptr,
                                                    int* __restrict__ bcur,
                                                    float* __restrict__ dinv,
                                                    int n, int nb, int E) {
    __shared__ int wtot[4];
    __shared__ int offsS;
    int tid = threadIdx.x;
    int lane = tid & 63, wv = tid >> 6;
    if (wv == 0) {                          // re-scan <=64 partials, keep ours
        int p = (lane < nb) ? part[lane] : 0;
        int s = p;
        for (int off = 1; off < 64; off <<= 1) {
            int t = __shfl_up(s, off, 64);
            if (lane >= off) s += t;
        }
        if (lane == (int)blockIdx.x) offsS = s - p;   // exclusive
        if (blockIdx.x == 0 && lane == 0) ptr[n] = E;
    }
    int base = blockIdx.x * SCAN_CHUNK + tid * 8;
    int d[8];
    int t8 = 0;
#pragma unroll
    for (int i = 0; i < 8; ++i) {
        int idx = base + i;
        d[i] = (idx < n) ? deg[idx] : 0;
        t8 += d[i];
    }
    int s = t8;
    for (int off = 1; off < 64; off <<= 1) {
        int t = __shfl_up(s, off, 64);
        if (lane >= off) s += t;
    }
    if (lane == 63) wtot[wv] = s;
    __syncthreads();
    int wpre = 0;
    for (int w = 0; w < 4; ++w) if (w < wv) wpre += wtot[w];
    int run = offsS + wpre + (s - t8);
#pragma unroll
    for (int i = 0; i < 8; ++i) {
        int idx = base + i;
        if (idx < n) {
            ptr[idx] = run;
            if ((idx & 127) == 0) bcur[idx >> 7] = run;   // bucket staging base
            dinv[idx] = rsqrtf((float)(d[i] + 1));        // +1 self loop
            run += d[i];
        }
    }
}

// fill phase A: bucket edges (128 cols/bucket) into contiguous per-bucket runs
__global__ __launch_bounds__(256) void k_fill_a(const int* __restrict__ row,
                                                const int* __restrict__ col,
                                                int* __restrict__ bcur,
                                                int2* __restrict__ stage, int E, int nb) {
    __shared__ int cnt[512];
    __shared__ int base[512];
    int tid = threadIdx.x;
    int e0 = blockIdx.x * FILL_CH;
    for (int i = tid; i < nb; i += 256) cnt[i] = 0;
    __syncthreads();
    int r[16], c[16];
#pragma unroll
    for (int i = 0; i < 16; ++i) {
        int e = e0 + tid + i * 256;
        if (e < E) {
            r[i] = row[e]; c[i] = col[e];
            atomicAdd(&cnt[c[i] >> 7], 1);
        } else c[i] = -1;
    }
    __syncthreads();
    for (int i = tid; i < nb; i += 256)
        base[i] = cnt[i] ? atomicAdd(&bcur[i], cnt[i]) : 0;
    __syncthreads();
    for (int i = tid; i < nb; i += 256) cnt[i] = 0;
    __syncthreads();
#pragma unroll
    for (int i = 0; i < 16; ++i) {
        if (c[i] >= 0) {
            int b = c[i] >> 7;
            int lp = atomicAdd(&cnt[b], 1);
            stage[base[b] + lp] = make_int2(r[i], c[i]);
        }
    }
}

// fill phase B: one block per bucket; LDS cursors; csr writes stay in one L2
__global__ __launch_bounds__(256) void k_fill_b(const int* __restrict__ ptr,
                                                const int2* __restrict__ stage,
                                                int* __restrict__ csr, int n) {
    __shared__ int lcur[128];
    int b = blockIdx.x;
    int tid = threadIdx.x;
    int c0 = b << 7;
    for (int j = tid; j < 128; j += 256) {
        int idx = c0 + j; if (idx > n) idx = n;
        lcur[j] = ptr[idx];
    }
    __syncthreads();
    int start = ptr[c0];
    int endi = c0 + 128; if (endi > n) endi = n;
    int end = ptr[endi];
    for (int p = start + tid; p < end; p += 256) {
        int2 rc = stage[p];
        int pos = atomicAdd(&lcur[rc.y & 127], 1);
        csr[pos] = rc.x;
    }
}

// irregular gather (fp16 x): agg[v] = dv*(sum dinv[r]*xh[r]) + dv^2*x[v]
// 8 edge slots x 8 lanes x half4; one-ahead index prefetch; fp32 accumulate
__global__ __launch_bounds__(256) void k_gather32(
        const int* __restrict__ ptr, const int* __restrict__ csr_row,
        const float* __restrict__ x, const _Float16* __restrict__ xh,
        const float* __restrict__ dinv, float* __restrict__ agg, int n) {
    int wid = blockIdx.x * 4 + (threadIdx.x >> 6);
    if (wid >= n) return;
    int lane = threadIdx.x & 63;
    int f4 = lane & 7, slot = lane >> 3;
    int v = wid;
    int start = ptr[v], end = ptr[v + 1];
    const f16x4* xh4 = (const f16x4*)xh;
    float sx = 0.f, sy = 0.f, sz = 0.f, sw = 0.f;
    int p = start + slot;
    int r = (p < end) ? csr_row[p] : 0;
    while (p < end) {
        int rcur = r;
        int pn = p + 8;
        if (pn < end) r = csr_row[pn];
        float dr = dinv[rcur];
        f16x4 xv = xh4[(size_t)rcur * 8 + f4];
        sx = fmaf(dr, (float)xv[0], sx);
        sy = fmaf(dr, (float)xv[1], sy);
        sz = fmaf(dr, (float)xv[2], sz);
        sw = fmaf(dr, (float)xv[3], sw);
        p = pn;
    }
#pragma unroll
    for (int off = 8; off < 64; off <<= 1) {
        sx += __shfl_xor(sx, off); sy += __shfl_xor(sy, off);
        sz += __shfl_xor(sz, off); sw += __shfl_xor(sw, off);
    }
    if (slot == 0) {
        float dv = dinv[v], d2 = dv * dv;
        float4 xv = ((const float4*)x)[(size_t)v * 8 + f4];   // self term fp32
        float4 o;
        o.x = dv * sx + d2 * xv.x;
        o.y = dv * sy + d2 * xv.y;
        o.z = dv * sz + d2 * xv.z;
        o.w = dv * sw + d2 * xv.w;
        ((float4*)agg)[(size_t)v * 8 + f4] = o;
    }
}

// dense MFMA: h1 = tanh(agg @ Wg1 + gb), tiles of 16 nodes, one wave/tile
__global__ __launch_bounds__(256) void k_h1(
        const float* __restrict__ agg, const float* __restrict__ gw,
        const float* __restrict__ gb, float* __restrict__ h1, int ntiles) {
    int wid = blockIdx.x * 4 + (threadIdx.x >> 6);
    if (wid >= ntiles) return;
    int lane = threadIdx.x & 63;
    int n16 = lane & 15, q = lane >> 4;

    short8 bh[4], bl[4];
    float bias[4];
#pragma unroll
    for (int t = 0; t < 4; ++t) {
        bias[t] = gb[t * 16 + n16];
        short8 hh, ll;
#pragma unroll
        for (int j = 0; j < 8; ++j) {
            float w = gw[(q * 8 + j) * 64 + t * 16 + n16];
            unsigned short wh = f2bf(w);
            hh[j] = (short)wh;
            ll[j] = (short)f2bf(w - bf2f(wh));
        }
        bh[t] = hh; bl[t] = ll;
    }

    int v0 = wid * 16;
    const float4* a4 = (const float4*)(agg + (size_t)(v0 + n16) * 32);
    float4 A0 = a4[2 * q], A1 = a4[2 * q + 1];
    float a[8] = {A0.x, A0.y, A0.z, A0.w, A1.x, A1.y, A1.z, A1.w};
    short8 ah, al;
#pragma unroll
    for (int j = 0; j < 8; ++j) { short h, l; splitT(a[j], h, l); ah[j] = h; al[j] = l; }

#pragma unroll
    for (int t = 0; t < 4; ++t) {
        f32x4 acc = (f32x4){bias[t], bias[t], bias[t], bias[t]};
        acc = __builtin_amdgcn_mfma_f32_16x16x32_bf16(ah, bh[t], acc, 0, 0, 0);
        acc = __builtin_amdgcn_mfma_f32_16x16x32_bf16(al, bh[t], acc, 0, 0, 0);
        acc = __builtin_amdgcn_mfma_f32_16x16x32_bf16(ah, bl[t], acc, 0, 0, 0);
#pragma unroll
        for (int i = 0; i < 4; ++i)
            h1[(size_t)(v0 + q * 4 + i) * 64 + t * 16 + n16] = tanhf(acc[i]);
    }
}

// dense MFMA (bf16 3-term ~fp32 internally): atab = h1@(W1a-W1b)+b1 ; btab = h1@W1b
// outputs stored as FP16 (RNE) for the fp16 edge MLP
__global__ __launch_bounds__(256, 1) void k_w1tab(
        const float* __restrict__ h1, const float* __restrict__ w1,
        const float* __restrict__ b1,
        _Float16* __restrict__ atab, _Float16* __restrict__ btab, int ntiles) {
    int lane = threadIdx.x & 63;
    int n16 = lane & 15, q = lane >> 4;

    short8 th[4][2], tl[4][2], uh[4][2], ul[4][2];   // wt=W1a-W1b, wb=W1b frags
    float bias[4];
#pragma unroll
    for (int t = 0; t < 4; ++t) {
        bias[t] = b1[t * 16 + n16];
#pragma unroll
        for (int ck = 0; ck < 2; ++ck) {
            short8 h1v, l1v, h2v, l2v;
#pragma unroll
            for (int j = 0; j < 8; ++j) {
                int d = ck * 32 + q * 8 + j;
                float wbv = w1[(64 + d) * 64 + t * 16 + n16];
                float wtv = w1[d * 64 + t * 16 + n16] - wbv;
                unsigned short x1 = f2bf(wtv);
                h1v[j] = (short)x1; l1v[j] = (short)f2bf(wtv - bf2f(x1));
                unsigned short x2 = f2bf(wbv);
                h2v[j] = (short)x2; l2v[j] = (short)f2bf(wbv - bf2f(x2));
            }
            th[t][ck] = h1v; tl[t][ck] = l1v;
            uh[t][ck] = h2v; ul[t][ck] = l2v;
        }
    }

    int nwaves = gridDim.x * 4;
    int wid = blockIdx.x * 4 + (threadIdx.x >> 6);
    for (int tile = wid; tile < ntiles; tile += nwaves) {
        int v0 = tile * 16;
        const float4* a4 = (const float4*)(h1 + (size_t)(v0 + n16) * 64);
        float4 A0 = a4[2 * q], A1 = a4[2 * q + 1];
        float4 A2 = a4[8 + 2 * q], A3 = a4[8 + 2 * q + 1];
        float a[16] = {A0.x, A0.y, A0.z, A0.w, A1.x, A1.y, A1.z, A1.w,
                       A2.x, A2.y, A2.z, A2.w, A3.x, A3.y, A3.z, A3.w};
        short8 ah0, ah1, al0, al1;
#pragma unroll
        for (int j = 0; j < 8; ++j) {
            short h, l;
            splitT(a[j], h, l);      ah0[j] = h; al0[j] = l;
            splitT(a[8 + j], h, l);  ah1[j] = h; al1[j] = l;
        }
#pragma unroll
        for (int t = 0; t < 4; ++t) {
            f32x4 aa = (f32x4){bias[t], bias[t], bias[t], bias[t]};
            aa = __builtin_amdgcn_mfma_f32_16x16x32_bf16(ah0, th[t][0], aa, 0, 0, 0);
            aa = __builtin_amdgcn_mfma_f32_16x16x32_bf16(ah1, th[t][1], aa, 0, 0, 0);
            aa = __builtin_amdgcn_mfma_f32_16x16x32_bf16(al0, th[t][0], aa, 0, 0, 0);
            aa = __builtin_amdgcn_mfma_f32_16x16x32_bf16(al1, th[t][1], aa, 0, 0, 0);
            aa = __builtin_amdgcn_mfma_f32_16x16x32_bf16(ah0, tl[t][0], aa, 0, 0, 0);
            aa = __builtin_amdgcn_mfma_f32_16x16x32_bf16(ah1, tl[t][1], aa, 0, 0, 0);
            f32x4 bb = (f32x4){0.f, 0.f, 0.f, 0.f};
            bb = __builtin_amdgcn_mfma_f32_16x16x32_bf16(ah0, uh[t][0], bb, 0, 0, 0);
            bb = __builtin_amdgcn_mfma_f32_16x16x32_bf16(ah1, uh[t][1], bb, 0, 0, 0);
            bb = __builtin_amdgcn_mfma_f32_16x16x32_bf16(al0, uh[t][0], bb, 0, 0, 0);
            bb = __builtin_amdgcn_mfma_f32_16x16x32_bf16(al1, uh[t][1], bb, 0, 0, 0);
            bb = __builtin_amdgcn_mfma_f32_16x16x32_bf16(ah0, ul[t][0], bb, 0, 0, 0);
            bb = __builtin_amdgcn_mfma_f32_16x16x32_bf16(ah1, ul[t][1], bb, 0, 0, 0);
#pragma unroll
            for (int i = 0; i < 4; ++i) {
                size_t off = (size_t)(v0 + q * 4 + i) * 64 + t * 16 + n16;
                atab[off] = (_Float16)aa[i];
                btab[off] = (_Float16)bb[i];
            }
        }
    }
}

// persistent waves; simple tile loop (best-measured variant); fp16 MFMA (fp32
// acc); fused GCN2 node matmul in epilogue; h2 stored fp16; no atomics
__global__ __launch_bounds__(256) void k_edge_mlp(
        const int* __restrict__ ptr, const int* __restrict__ csr_row,
        const _Float16* __restrict__ atab, const _Float16* __restrict__ btab,
        const float* __restrict__ w2, const float* __restrict__ b2,
        const float* __restrict__ wg, _Float16* __restrict__ h2h, int n) {
    int lane = threadIdx.x & 63;
    int n16 = lane & 15, q = lane >> 4;

    f16x8 wh[4][2];
    float bias[4];
    float wgf[4][4];    // Wg2 rows {t*16+n16}, cols {q*4+jj}
#pragma unroll
    for (int t = 0; t < 4; ++t) {
        bias[t] = b2[t * 16 + n16];
#pragma unroll
        for (int jj = 0; jj < 4; ++jj)
            wgf[t][jj] = wg[(t * 16 + n16) * 16 + q * 4 + jj];
#pragma unroll
        for (int ck = 0; ck < 2; ++ck) {
            f16x8 hh;
#pragma unroll
            for (int j = 0; j < 8; ++j)
                hh[j] = (_Float16)w2[(ck * 32 + q * 8 + j) * 64 + t * 16 + n16];
            wh[t][ck] = hh;
        }
    }

    int nwaves = gridDim.x * 4;
    int wid = blockIdx.x * 4 + (threadIdx.x >> 6);

    for (int c = wid; c < n; c += nwaves) {
        int st = ptr[c], ed = ptr[c + 1];
        const f16x8* a8 = (const f16x8*)(atab + (size_t)c * 64);
        f16x8 A0 = a8[q], A1 = a8[4 + q];
        float red[4] = {0.f, 0.f, 0.f, 0.f};   // init 0 folds relu + empty-segment-0

        int p0 = st;
        int nfull = (ed - st) >> 4;
        for (int ft = 0; ft < nfull; ++ft, p0 += 16) {
            int r = csr_row[p0 + n16];
            const f16x8* b8 = (const f16x8*)(btab + (size_t)r * 64);
            f16x8 u0 = relu8(A0 + b8[q]);
            f16x8 u1 = relu8(A1 + b8[4 + q]);
#pragma unroll
            for (int t = 0; t < 4; ++t) {
                f32x4 acc = (f32x4){bias[t], bias[t], bias[t], bias[t]};
                acc = __builtin_amdgcn_mfma_f32_16x16x32_f16(u0, wh[t][0], acc, 0, 0, 0);
                acc = __builtin_amdgcn_mfma_f32_16x16x32_f16(u1, wh[t][1], acc, 0, 0, 0);
                red[t] = fmaxf(red[t], fmaxf(fmaxf(acc[0], acc[1]), fmaxf(acc[2], acc[3])));
            }
        }
        int rem = ed - p0;
        if (rem > 0) {
            f16x8 u0 = {0, 0, 0, 0, 0, 0, 0, 0};
            f16x8 u1 = {0, 0, 0, 0, 0, 0, 0, 0};
            if (n16 < rem) {
                int r = csr_row[p0 + n16];
                const f16x8* b8 = (const f16x8*)(btab + (size_t)r * 64);
                u0 = relu8(A0 + b8[q]);
                u1 = relu8(A1 + b8[4 + q]);
            }
#pragma unroll
            for (int t = 0; t < 4; ++t) {
                f32x4 acc = (f32x4){bias[t], bias[t], bias[t], bias[t]};
                acc = __builtin_amdgcn_mfma_f32_16x16x32_f16(u0, wh[t][0], acc, 0, 0, 0);
                acc = __builtin_amdgcn_mfma_f32_16x16x32_f16(u1, wh[t][1], acc, 0, 0, 0);
#pragma unroll
                for (int i = 0; i < 4; ++i)
                    if (q * 4 + i < rem) red[t] = fmaxf(red[t], acc[i]);
            }
        }
        // butterfly: all lanes get final segment-max for features t*16+n16
#pragma unroll
        for (int t = 0; t < 4; ++t) {
            red[t] = fmaxf(red[t], __shfl_xor(red[t], 16));
            red[t] = fmaxf(red[t], __shfl_xor(red[t], 32));
        }
        // fused GCN2 node matmul: h2[c][q*4+jj] = sum_d hmax[d]*wg[d][q*4+jj]
        float part[4];
#pragma unroll
        for (int jj = 0; jj < 4; ++jj) {
            part[jj] = red[0] * wgf[0][jj];
            part[jj] = fmaf(red[1], wgf[1][jj], part[jj]);
            part[jj] = fmaf(red[2], wgf[2][jj], part[jj]);
            part[jj] = fmaf(red[3], wgf[3][jj], part[jj]);
        }
#pragma unroll
        for (int off = 1; off < 16; off <<= 1)
#pragma unroll
            for (int jj = 0; jj < 4; ++jj)
                part[jj] += __shfl_xor(part[jj], off);
        if (n16 == 0) {
            f16x4 ph;
            ph[0] = (_Float16)part[0]; ph[1] = (_Float16)part[1];
            ph[2] = (_Float16)part[2]; ph[3] = (_Float16)part[3];
            ((f16x4*)(h2h + (size_t)c * 16))[q] = ph;
        }
    }
}

// out[c] = bg + dv*(dv*h2[c] + sum_in dinv[r]*h2[r]) ; fully writes d_out
__global__ __launch_bounds__(256) void k_gcn2_gather(
        const int* __restrict__ ptr, const int* __restrict__ csr_row,
        const _Float16* __restrict__ h2h, const float* __restrict__ dinv,
        const float* __restrict__ bg, float* __restrict__ out, int n) {
    int wid = blockIdx.x * 4 + (threadIdx.x >> 6);
    if (wid >= n) return;
    int lane = threadIdx.x & 63;
    int f2 = lane & 7, slot = lane >> 3;
    int c = wid;
    int start = ptr[c], end = ptr[c + 1];
    const f16x2* h22 = (const f16x2*)h2h;
    float sx = 0.f, sy = 0.f;
    int p = start + slot;
    int r = (p < end) ? csr_row[p] : 0;
    while (p < end) {
        int rcur = r;
        int pn = p + 8;
        if (pn < end) r = csr_row[pn];
        float dr = dinv[rcur];
        f16x2 hv = h22[(size_t)rcur * 8 + f2];
        sx = fmaf(dr, (float)hv[0], sx);
        sy = fmaf(dr, (float)hv[1], sy);
        p = pn;
    }
#pragma unroll
    for (int off = 8; off < 64; off <<= 1) {
        sx += __shfl_xor(sx, off);
        sy += __shfl_xor(sy, off);
    }
    if (slot == 0) {
        float dv = dinv[c];
        f16x2 hv = h22[(size_t)c * 8 + f2];
        float2 o;
        o.x = bg[2 * f2]     + dv * (dv * (float)hv[0] + sx);
        o.y = bg[2 * f2 + 1] + dv * (dv * (float)hv[1] + sy);
        ((float2*)out)[(size_t)c * 8 + f2] = o;
    }
}

extern "C" void kernel_launch(void* const* d_in, const int* in_sizes, int n_in,
                              void* d_out, int out_size, void* d_ws, size_t ws_size,
                              hipStream_t stream) {
    const float* x   = (const float*)d_in[0];
    const int*   ei  = (const int*)d_in[1];
    const float* g1w = (const float*)d_in[2];
    const float* g1b = (const float*)d_in[3];
    const float* ew1 = (const float*)d_in[4];
    const float* eb1 = (const float*)d_in[5];
    const float* ew2 = (const float*)d_in[6];
    const float* eb2 = (const float*)d_in[7];
    const float* g2w = (const float*)d_in[8];
    const float* g2b = (const float*)d_in[9];
    float* out = (float*)d_out;
    float* ws  = (float*)d_ws;

    const int n = in_sizes[0] / 32;      // 50000
    const int E = in_sizes[1] / 2;       // 800000
    const int* row = ei;
    const int* col = ei + E;
    const int ntiles = (n + 15) / 16;    // 3125
    const int nbuck = (n + 127) >> 7;    // 391 buckets of 128 cols

    size_t npad    = ((size_t)n + 63) & ~(size_t)63;
    size_t o_deg   = 0;
    size_t o_ptr   = npad;                      // n+1 (+pad)
    size_t o_csr   = o_ptr + npad + 64;         // E ints
    size_t o_dinv  = o_csr + (size_t)E;
    size_t o_h1    = o_dinv + npad;             // n*64 fp32
    size_t o_atab  = o_h1 + (size_t)n * 64;     // n*64 fp16 = n*32 floats
    size_t o_btab  = o_atab + (size_t)n * 32;   // n*64 fp16
    size_t o_agg   = o_btab + (size_t)n * 32;   // n*32 fp32
    size_t o_xh    = o_agg + (size_t)n * 32;    // n*32 fp16 = n*16 floats
    size_t o_h2h   = o_xh + (size_t)n * 16;     // n*16 fp16 = n*8 floats
    size_t o_stage = o_h2h + (size_t)n * 8;     // E int2 (8B aligned: offsets even)
    size_t o_bcur  = o_stage + (size_t)E * 2;   // nbuck ints
    size_t o_part  = o_bcur + 512;              // 64 ints

    int*      deg    = (int*)(ws + o_deg);
    int*      ptr    = (int*)(ws + o_ptr);
    int*      csr    = (int*)(ws + o_csr);
    float*    dinv   = ws + o_dinv;
    float*    h1     = ws + o_h1;
    _Float16* atab   = (_Float16*)(ws + o_atab);
    _Float16* btab   = (_Float16*)(ws + o_btab);
    float*    agg    = ws + o_agg;
    _Float16* xh     = (_Float16*)(ws + o_xh);
    _Float16* h2h    = (_Float16*)(ws + o_h2h);
    int2*     stage  = (int2*)(ws + o_stage);
    int*      bcur   = (int*)(ws + o_bcur);
    int*      part   = (int*)(ws + o_part);

    int nblk = (n + 3) / 4;                      // wave-per-node kernels, 4 waves/block
    int tblk = (ntiles + 3) / 4;
    int scan_nb = (n + SCAN_CHUNK - 1) / SCAN_CHUNK;   // 25 <= 64
    int fill_nb = (E + FILL_CH - 1) / FILL_CH;         // 196
    int m4 = n * 8;                                    // x float4 count

    hipMemsetAsync(deg, 0, npad * sizeof(int), stream);
    k_deg_cast<<<(E + 255) / 256, 256, 0, stream>>>(col, deg, (const float4*)x,
                                                    (f16x4*)xh, E, m4);
    k_scan_partial<<<scan_nb, 256, 0, stream>>>(deg, part, n);
    k_scan_final<<<scan_nb, 256, 0, stream>>>(deg, part, ptr, bcur, dinv, n, scan_nb, E);
    k_fill_a<<<fill_nb, 256, 0, stream>>>(row, col, bcur, stage, E, nbuck);
    k_fill_b<<<nbuck, 256, 0, stream>>>(ptr, stage, csr, n);
    k_gather32<<<nblk, 256, 0, stream>>>(ptr, csr, x, xh, dinv, agg, n);
    k_h1<<<tblk, 256, 0, stream>>>(agg, g1w, g1b, h1, ntiles);
    k_w1tab<<<256, 256, 0, stream>>>(h1, ew1, eb1, atab, btab, ntiles);
    k_edge_mlp<<<2048, 256, 0, stream>>>(ptr, csr, atab, btab, ew2, eb2, g2w, h2h, n);
    k_gcn2_gather<<<nblk, 256, 0, stream>>>(ptr, csr, h2h, dinv, g2b, out, n);
}

// Round 20
// 233.490 us; speedup vs baseline: 1.9868x; 1.0080x over previous
//
#include <hip/hip_runtime.h>

// CSR-gather pipeline (no float atomics), 9 stream nodes:
//   memset(deg) ; deg_cast (deg hist + x->fp16) ; scan_partial ; scan_final ;
//   fill_a ; fill_b (bucketed CSR) ; gather32 ; h1tab (fused h1 + W1-split tables,
//   LDS layout round-trip) ; edge_mlp (fp16 MFMA + fused GCN2) ; gcn2_gather

typedef __attribute__((ext_vector_type(8))) short short8;
typedef __attribute__((ext_vector_type(4))) float f32x4;
typedef __attribute__((ext_vector_type(8))) _Float16 f16x8;
typedef __attribute__((ext_vector_type(4))) _Float16 f16x4;
typedef __attribute__((ext_vector_type(2))) _Float16 f16x2;

#define SCAN_CHUNK 2048   // elements per scan block (256 thr x 8)
#define FILL_CH 4096      // edges per phase-A block (256 thr x 16)

__device__ __forceinline__ unsigned short f2bf(float x) {   // RNE f32->bf16 (cold paths only)
    unsigned int u = __float_as_uint(x);
    return (unsigned short)((u + 0x7FFFu + ((u >> 16) & 1u)) >> 16);
}
__device__ __forceinline__ float bf2f(unsigned short h) {
    return __uint_as_float(((unsigned int)h) << 16);
}
// cheap truncation split: u ~= hi + lo with |err| ~ 2^-16 |u|
__device__ __forceinline__ void splitT(float u, short& hi, short& lo) {
    unsigned int ub = __float_as_uint(u);
    hi = (short)(ub >> 16);
    float r = u - __uint_as_float(ub & 0xFFFF0000u);
    lo = (short)(__float_as_uint(r) >> 16);
}
__device__ __forceinline__ f16x8 relu8(f16x8 v) {
    f16x8 z = {0, 0, 0, 0, 0, 0, 0, 0};
#if __has_builtin(__builtin_elementwise_max)
    return __builtin_elementwise_max(v, z);
#else
    f16x8 o;
#pragma unroll
    for (int j = 0; j < 8; ++j) o[j] = v[j] > (_Float16)0 ? v[j] : (_Float16)0;
    return o;
#endif
}

// fused: degree histogram + x -> fp16 cast
__global__ void k_deg_cast(const int* __restrict__ col, int* __restrict__ deg,
                           const float4* __restrict__ x4, f16x4* __restrict__ xh4,
                           int E, int m4) {
    int e = blockIdx.x * blockDim.x + threadIdx.x;
    if (e < m4) {
        float4 v = x4[e];
        f16x4 o;
        o[0] = (_Float16)v.x; o[1] = (_Float16)v.y;
        o[2] = (_Float16)v.z; o[3] = (_Float16)v.w;
        xh4[e] = o;
    }
    if (e < E) atomicAdd(&deg[col[e]], 1);
}

__global__ __launch_bounds__(256) void k_scan_partial(const int* __restrict__ deg,
                                                      int* __restrict__ part, int n) {
    __shared__ int wtot[4];
    int tid = threadIdx.x;
    int base = blockIdx.x * SCAN_CHUNK + tid * 8;
    int s = 0;
#pragma unroll
    for (int i = 0; i < 8; ++i) { int idx = base + i; if (idx < n) s += deg[idx]; }
    for (int off = 1; off < 64; off <<= 1) s += __shfl_xor(s, off);
    if ((tid & 63) == 0) wtot[tid >> 6] = s;
    __syncthreads();
    if (tid == 0) part[blockIdx.x] = wtot[0] + wtot[1] + wtot[2] + wtot[3];
}

// merged: per-block offset from partials (wave 0, in-register) + block-local
// exclusive scan + ptr + bcur + dinv
__global__ __launch_bounds__(256) void k_scan_final(const int* __restrict__ deg,
                                                    const int* __restrict__ part,
                                                    int* __restrict__ ptr,
                                                    int* __restrict__ bcur,
                                                    float* __restrict__ dinv,
                                                    int n, int nb, int E) {
    __shared__ int wtot[4];
    __shared__ int offsS;
    int tid = threadIdx.x;
    int lane = tid & 63, wv = tid >> 6;
    if (wv == 0) {                          // re-scan <=64 partials, keep ours
        int p = (lane < nb) ? part[lane] : 0;
        int s = p;
        for (int off = 1; off < 64; off <<= 1) {
            int t = __shfl_up(s, off, 64);
            if (lane >= off) s += t;
        }
        if (lane == (int)blockIdx.x) offsS = s - p;   // exclusive
        if (blockIdx.x == 0 && lane == 0) ptr[n] = E;
    }
    int base = blockIdx.x * SCAN_CHUNK + tid * 8;
    int d[8];
    int t8 = 0;
#pragma unroll
    for (int i = 0; i < 8; ++i) {
        int idx = base + i;
        d[i] = (idx < n) ? deg[idx] : 0;
        t8 += d[i];
    }
    int s = t8;
    for (int off = 1; off < 64; off <<= 1) {
        int t = __shfl_up(s, off, 64);
        if (lane >= off) s += t;
    }
    if (lane == 63) wtot[wv] = s;
    __syncthreads();
    int wpre = 0;
    for (int w = 0; w < 4; ++w) if (w < wv) wpre += wtot[w];
    int run = offsS + wpre + (s - t8);
#pragma unroll
    for (int i = 0; i < 8; ++i) {
        int idx = base + i;
        if (idx < n) {
            ptr[idx] = run;
            if ((idx & 127) == 0) bcur[idx >> 7] = run;   // bucket staging base
            dinv[idx] = rsqrtf((float)(d[i] + 1));        // +1 self loop
            run += d[i];
        }
    }
}

// fill phase A: bucket edges (128 cols/bucket) into contiguous per-bucket runs
__global__ __launch_bounds__(256) void k_fill_a(const int* __restrict__ row,
                                                const int* __restrict__ col,
                                                int* __restrict__ bcur,
                                                int2* __restrict__ stage, int E, int nb) {
    __shared__ int cnt[512];
    __shared__ int base[512];
    int tid = threadIdx.x;
    int e0 = blockIdx.x * FILL_CH;
    for (int i = tid; i < nb; i += 256) cnt[i] = 0;
    __syncthreads();
    int r[16], c[16];
#pragma unroll
    for (int i = 0; i < 16; ++i) {
        int e = e0 + tid + i * 256;
        if (e < E) {
            r[i] = row[e]; c[i] = col[e];
            atomicAdd(&cnt[c[i] >> 7], 1);
        } else c[i] = -1;
    }
    __syncthreads();
    for (int i = tid; i < nb; i += 256)
        base[i] = cnt[i] ? atomicAdd(&bcur[i], cnt[i]) : 0;
    __syncthreads();
    for (int i = tid; i < nb; i += 256) cnt[i] = 0;
    __syncthreads();
#pragma unroll
    for (int i = 0; i < 16; ++i) {
        if (c[i] >= 0) {
            int b = c[i] >> 7;
            int lp = atomicAdd(&cnt[b], 1);
            stage[base[b] + lp] = make_int2(r[i], c[i]);
        }
    }
}

// fill phase B: one block per bucket; LDS cursors; csr writes stay in one L2
__global__ __launch_bounds__(256) void k_fill_b(const int* __restrict__ ptr,
                                                const int2* __restrict__ stage,
                                                int* __restrict__ csr, int n) {
    __shared__ int lcur[128];
    int b = blockIdx.x;
    int tid = threadIdx.x;
    int c0 = b << 7;
    for (int j = tid; j < 128; j += 256) {
        int idx = c0 + j; if (idx > n) idx = n;
        lcur[j] = ptr[idx];
    }
    __syncthreads();
    int start = ptr[c0];
    int endi = c0 + 128; if (endi > n) endi = n;
    int end = ptr[endi];
    for (int p = start + tid; p < end; p += 256) {
        int2 rc = stage[p];
        int pos = atomicAdd(&lcur[rc.y & 127], 1);
        csr[pos] = rc.x;
    }
}

// irregular gather (fp16 x): agg[v] = dv*(sum dinv[r]*xh[r]) + dv^2*x[v]
// 8 edge slots x 8 lanes x half4; one-ahead index prefetch; fp32 accumulate
__global__ __launch_bounds__(256) void k_gather32(
        const int* __restrict__ ptr, const int* __restrict__ csr_row,
        const float* __restrict__ x, const _Float16* __restrict__ xh,
        const float* __restrict__ dinv, float* __restrict__ agg, int n) {
    int wid = blockIdx.x * 4 + (threadIdx.x >> 6);
    if (wid >= n) return;
    int lane = threadIdx.x & 63;
    int f4 = lane & 7, slot = lane >> 3;
    int v = wid;
    int start = ptr[v], end = ptr[v + 1];
    const f16x4* xh4 = (const f16x4*)xh;
    float sx = 0.f, sy = 0.f, sz = 0.f, sw = 0.f;
    int p = start + slot;
    int r = (p < end) ? csr_row[p] : 0;
    while (p < end) {
        int rcur = r;
        int pn = p + 8;
        if (pn < end) r = csr_row[pn];
        float dr = dinv[rcur];
        f16x4 xv = xh4[(size_t)rcur * 8 + f4];
        sx = fmaf(dr, (float)xv[0], sx);
        sy = fmaf(dr, (float)xv[1], sy);
        sz = fmaf(dr, (float)xv[2], sz);
        sw = fmaf(dr, (float)xv[3], sw);
        p = pn;
    }
#pragma unroll
    for (int off = 8; off < 64; off <<= 1) {
        sx += __shfl_xor(sx, off); sy += __shfl_xor(sy, off);
        sz += __shfl_xor(sz, off); sw += __shfl_xor(sw, off);
    }
    if (slot == 0) {
        float dv = dinv[v], d2 = dv * dv;
        float4 xv = ((const float4*)x)[(size_t)v * 8 + f4];   // self term fp32
        float4 o;
        o.x = dv * sx + d2 * xv.x;
        o.y = dv * sy + d2 * xv.y;
        o.z = dv * sz + d2 * xv.z;
        o.w = dv * sw + d2 * xv.w;
        ((float4*)agg)[(size_t)v * 8 + f4] = o;
    }
}

// FUSED dense MFMA: h1 = tanh(agg @ Wg1 + gb)  then  atab = h1@(W1a-W1b)+b1 ;
// btab = h1@W1b (fp16 out). h1 never leaves the CU: C/D -> A layout transform
// via wave-private LDS tile (16 x 66, pad keeps <=2-way bank aliasing).
__global__ __launch_bounds__(256, 1) void k_h1tab(
        const float* __restrict__ agg, const float* __restrict__ gw,
        const float* __restrict__ gb, const float* __restrict__ w1,
        const float* __restrict__ b1,
        _Float16* __restrict__ atab, _Float16* __restrict__ btab, int ntiles) {
    __shared__ float tileS[4][16 * 66];
    int lane = threadIdx.x & 63;
    int wv = threadIdx.x >> 6;
    int n16 = lane & 15, q = lane >> 4;
    float* T = tileS[wv];

    // Wg1 frags (bf16 3-term) + gb
    short8 gh[4], gl[4];
    float gbias[4];
#pragma unroll
    for (int t = 0; t < 4; ++t) {
        gbias[t] = gb[t * 16 + n16];
        short8 hh, ll;
#pragma unroll
        for (int j = 0; j < 8; ++j) {
            float w = gw[(q * 8 + j) * 64 + t * 16 + n16];
            unsigned short wh = f2bf(w);
            hh[j] = (short)wh;
            ll[j] = (short)f2bf(w - bf2f(wh));
        }
        gh[t] = hh; gl[t] = ll;
    }
    // W1 frags (bf16 3-term, wt=W1a-W1b and wb=W1b) + b1
    short8 th[4][2], tl[4][2], uh[4][2], ul[4][2];
    float bias1[4];
#pragma unroll
    for (int t = 0; t < 4; ++t) {
        bias1[t] = b1[t * 16 + n16];
#pragma unroll
        for (int ck = 0; ck < 2; ++ck) {
            short8 h1v, l1v, h2v, l2v;
#pragma unroll
            for (int j = 0; j < 8; ++j) {
                int d = ck * 32 + q * 8 + j;
                float wbv = w1[(64 + d) * 64 + t * 16 + n16];
                float wtv = w1[d * 64 + t * 16 + n16] - wbv;
                unsigned short x1 = f2bf(wtv);
                h1v[j] = (short)x1; l1v[j] = (short)f2bf(wtv - bf2f(x1));
                unsigned short x2 = f2bf(wbv);
                h2v[j] = (short)x2; l2v[j] = (short)f2bf(wbv - bf2f(x2));
            }
            th[t][ck] = h1v; tl[t][ck] = l1v;
            uh[t][ck] = h2v; ul[t][ck] = l2v;
        }
    }

    int nwaves = gridDim.x * 4;
    int wid = blockIdx.x * 4 + wv;
    for (int tile = wid; tile < ntiles; tile += nwaves) {
        int v0 = tile * 16;
        // GEMM1: h1 tile in C/D layout -> LDS
        const float4* a4 = (const float4*)(agg + (size_t)(v0 + n16) * 32);
        float4 A0 = a4[2 * q], A1 = a4[2 * q + 1];
        float a[8] = {A0.x, A0.y, A0.z, A0.w, A1.x, A1.y, A1.z, A1.w};
        short8 ah, al;
#pragma unroll
        for (int j = 0; j < 8; ++j) { short h, l; splitT(a[j], h, l); ah[j] = h; al[j] = l; }
#pragma unroll
        for (int t = 0; t < 4; ++t) {
            f32x4 acc = (f32x4){gbias[t], gbias[t], gbias[t], gbias[t]};
            acc = __builtin_amdgcn_mfma_f32_16x16x32_bf16(ah, gh[t], acc, 0, 0, 0);
            acc = __builtin_amdgcn_mfma_f32_16x16x32_bf16(al, gh[t], acc, 0, 0, 0);
            acc = __builtin_amdgcn_mfma_f32_16x16x32_bf16(ah, gl[t], acc, 0, 0, 0);
#pragma unroll
            for (int i = 0; i < 4; ++i)
                T[(q * 4 + i) * 66 + t * 16 + n16] = tanhf(acc[i]);
        }
        // (wave-private LDS region: lgkmcnt ordering suffices, no barrier)
        // GEMM2: read h1 row n16 in A layout (k = ck*32 + q*8 + j)
        float b[16];
#pragma unroll
        for (int j = 0; j < 8; ++j) {
            b[j]     = T[n16 * 66 + q * 8 + j];
            b[8 + j] = T[n16 * 66 + 32 + q * 8 + j];
        }
        short8 ah0, ah1, al0, al1;
#pragma unroll
        for (int j = 0; j < 8; ++j) {
            short h, l;
            splitT(b[j], h, l);      ah0[j] = h; al0[j] = l;
            splitT(b[8 + j], h, l);  ah1[j] = h; al1[j] = l;
        }
#pragma unroll
        for (int t = 0; t < 4; ++t) {
            f32x4 aa = (f32x4){bias1[t], bias1[t], bias1[t], bias1[t]};
            aa = __builtin_amdgcn_mfma_f32_16x16x32_bf16(ah0, th[t][0], aa, 0, 0, 0);
            aa = __builtin_amdgcn_mfma_f32_16x16x32_bf16(ah1, th[t][1], aa, 0, 0, 0);
            aa = __builtin_amdgcn_mfma_f32_16x16x32_bf16(al0, th[t][0], aa, 0, 0, 0);
            aa = __builtin_amdgcn_mfma_f32_16x16x32_bf16(al1, th[t][1], aa, 0, 0, 0);
            aa = __builtin_amdgcn_mfma_f32_16x16x32_bf16(ah0, tl[t][0], aa, 0, 0, 0);
            aa = __builtin_amdgcn_mfma_f32_16x16x32_bf16(ah1, tl[t][1], aa, 0, 0, 0);
            f32x4 bb = (f32x4){0.f, 0.f, 0.f, 0.f};
            bb = __builtin_amdgcn_mfma_f32_16x16x32_bf16(ah0, uh[t][0], bb, 0, 0, 0);
            bb = __builtin_amdgcn_mfma_f32_16x16x32_bf16(ah1, uh[t][1], bb, 0, 0, 0);
            bb = __builtin_amdgcn_mfma_f32_16x16x32_bf16(al0, uh[t][0], bb, 0, 0, 0);
            bb = __builtin_amdgcn_mfma_f32_16x16x32_bf16(al1, uh[t][1], bb, 0, 0, 0);
            bb = __builtin_amdgcn_mfma_f32_16x16x32_bf16(ah0, ul[t][0], bb, 0, 0, 0);
            bb = __builtin_amdgcn_mfma_f32_16x16x32_bf16(ah1, ul[t][1], bb, 0, 0, 0);
#pragma unroll
            for (int i = 0; i < 4; ++i) {
                size_t off = (size_t)(v0 + q * 4 + i) * 64 + t * 16 + n16;
                atab[off] = (_Float16)aa[i];
                btab[off] = (_Float16)bb[i];
            }
        }
    }
}

// persistent waves; simple tile loop (best-measured variant); fp16 MFMA (fp32
// acc); fused GCN2 node matmul in epilogue; h2 stored fp16; no atomics
__global__ __launch_bounds__(256) void k_edge_mlp(
        const int* __restrict__ ptr, const int* __restrict__ csr_row,
        const _Float16* __restrict__ atab, const _Float16* __restrict__ btab,
        const float* __restrict__ w2, const float* __restrict__ b2,
        const float* __restrict__ wg, _Float16* __restrict__ h2h, int n) {
    int lane = threadIdx.x & 63;
    int n16 = lane & 15, q = lane >> 4;

    f16x8 wh[4][2];
    float bias[4];
    float wgf[4][4];    // Wg2 rows {t*16+n16}, cols {q*4+jj}
#pragma unroll
    for (int t = 0; t < 4; ++t) {
        bias[t] = b2[t * 16 + n16];
#pragma unroll
        for (int jj = 0; jj < 4; ++jj)
            wgf[t][jj] = wg[(t * 16 + n16) * 16 + q * 4 + jj];
#pragma unroll
        for (int ck = 0; ck < 2; ++ck) {
            f16x8 hh;
#pragma unroll
            for (int j = 0; j < 8; ++j)
                hh[j] = (_Float16)w2[(ck * 32 + q * 8 + j) * 64 + t * 16 + n16];
            wh[t][ck] = hh;
        }
    }

    int nwaves = gridDim.x * 4;
    int wid = blockIdx.x * 4 + (threadIdx.x >> 6);

    for (int c = wid; c < n; c += nwaves) {
        int st = ptr[c], ed = ptr[c + 1];
        const f16x8* a8 = (const f16x8*)(atab + (size_t)c * 64);
        f16x8 A0 = a8[q], A1 = a8[4 + q];
        float red[4] = {0.f, 0.f, 0.f, 0.f};   // init 0 folds relu + empty-segment-0

        int p0 = st;
        int nfull = (ed - st) >> 4;
        for (int ft = 0; ft < nfull; ++ft, p0 += 16) {
            int r = csr_row[p0 + n16];
            const f16x8* b8 = (const f16x8*)(btab + (size_t)r * 64);
            f16x8 u0 = relu8(A0 + b8[q]);
            f16x8 u1 = relu8(A1 + b8[4 + q]);
#pragma unroll
            for (int t = 0; t < 4; ++t) {
                f32x4 acc = (f32x4){bias[t], bias[t], bias[t], bias[t]};
                acc = __builtin_amdgcn_mfma_f32_16x16x32_f16(u0, wh[t][0], acc, 0, 0, 0);
                acc = __builtin_amdgcn_mfma_f32_16x16x32_f16(u1, wh[t][1], acc, 0, 0, 0);
                red[t] = fmaxf(red[t], fmaxf(fmaxf(acc[0], acc[1]), fmaxf(acc[2], acc[3])));
            }
        }
        int rem = ed - p0;
        if (rem > 0) {
            f16x8 u0 = {0, 0, 0, 0, 0, 0, 0, 0};
            f16x8 u1 = {0, 0, 0, 0, 0, 0, 0, 0};
            if (n16 < rem) {
                int r = csr_row[p0 + n16];
                const f16x8* b8 = (const f16x8*)(btab + (size_t)r * 64);
                u0 = relu8(A0 + b8[q]);
                u1 = relu8(A1 + b8[4 + q]);
            }
#pragma unroll
            for (int t = 0; t < 4; ++t) {
                f32x4 acc = (f32x4){bias[t], bias[t], bias[t], bias[t]};
                acc = __builtin_amdgcn_mfma_f32_16x16x32_f16(u0, wh[t][0], acc, 0, 0, 0);
                acc = __builtin_amdgcn_mfma_f32_16x16x32_f16(u1, wh[t][1], acc, 0, 0, 0);
#pragma unroll
                for (int i = 0; i < 4; ++i)
                    if (q * 4 + i < rem) red[t] = fmaxf(red[t], acc[i]);
            }
        }
        // butterfly: all lanes get final segment-max for features t*16+n16
#pragma unroll
        for (int t = 0; t < 4; ++t) {
            red[t] = fmaxf(red[t], __shfl_xor(red[t], 16));
            red[t] = fmaxf(red[t], __shfl_xor(red[t], 32));
        }
        // fused GCN2 node matmul: h2[c][q*4+jj] = sum_d hmax[d]*wg[d][q*4+jj]
        float part[4];
#pragma unroll
        for (int jj = 0; jj < 4; ++jj) {
            part[jj] = red[0] * wgf[0][jj];
            part[jj] = fmaf(red[1], wgf[1][jj], part[jj]);
            part[jj] = fmaf(red[2], wgf[2][jj], part[jj]);
            part[jj] = fmaf(red[3], wgf[3][jj], part[jj]);
        }
#pragma unroll
        for (int off = 1; off < 16; off <<= 1)
#pragma unroll
            for (int jj = 0; jj < 4; ++jj)
                part[jj] += __shfl_xor(part[jj], off);
        if (n16 == 0) {
            f16x4 ph;
            ph[0] = (_Float16)part[0]; ph[1] = (_Float16)part[1];
            ph[2] = (_Float16)part[2]; ph[3] = (_Float16)part[3];
            ((f16x4*)(h2h + (size_t)c * 16))[q] = ph;
        }
    }
}

// out[c] = bg + dv*(dv*h2[c] + sum_in dinv[r]*h2[r]) ; fully writes d_out
__global__ __launch_bounds__(256) void k_gcn2_gather(
        const int* __restrict__ ptr, const int* __restrict__ csr_row,
        const _Float16* __restrict__ h2h, const float* __restrict__ dinv,
        const float* __restrict__ bg, float* __restrict__ out, int n) {
    int wid = blockIdx.x * 4 + (threadIdx.x >> 6);
    if (wid >= n) return;
    int lane = threadIdx.x & 63;
    int f2 = lane & 7, slot = lane >> 3;
    int c = wid;
    int start = ptr[c], end = ptr[c + 1];
    const f16x2* h22 = (const f16x2*)h2h;
    float sx = 0.f, sy = 0.f;
    int p = start + slot;
    int r = (p < end) ? csr_row[p] : 0;
    while (p < end) {
        int rcur = r;
        int pn = p + 8;
        if (pn < end) r = csr_row[pn];
        float dr = dinv[rcur];
        f16x2 hv = h22[(size_t)rcur * 8 + f2];
        sx = fmaf(dr, (float)hv[0], sx);
        sy = fmaf(dr, (float)hv[1], sy);
        p = pn;
    }
#pragma unroll
    for (int off = 8; off < 64; off <<= 1) {
        sx += __shfl_xor(sx, off);
        sy += __shfl_xor(sy, off);
    }
    if (slot == 0) {
        float dv = dinv[c];
        f16x2 hv = h22[(size_t)c * 8 + f2];
        float2 o;
        o.x = bg[2 * f2]     + dv * (dv * (float)hv[0] + sx);
        o.y = bg[2 * f2 + 1] + dv * (dv * (float)hv[1] + sy);
        ((float2*)out)[(size_t)c * 8 + f2] = o;
    }
}

extern "C" void kernel_launch(void* const* d_in, const int* in_sizes, int n_in,
                              void* d_out, int out_size, void* d_ws, size_t ws_size,
                              hipStream_t stream) {
    const float* x   = (const float*)d_in[0];
    const int*   ei  = (const int*)d_in[1];
    const float* g1w = (const float*)d_in[2];
    const float* g1b = (const float*)d_in[3];
    const float* ew1 = (const float*)d_in[4];
    const float* eb1 = (const float*)d_in[5];
    const float* ew2 = (const float*)d_in[6];
    const float* eb2 = (const float*)d_in[7];
    const float* g2w = (const float*)d_in[8];
    const float* g2b = (const float*)d_in[9];
    float* out = (float*)d_out;
    float* ws  = (float*)d_ws;

    const int n = in_sizes[0] / 32;      // 50000
    const int E = in_sizes[1] / 2;       // 800000
    const int* row = ei;
    const int* col = ei + E;
    const int ntiles = (n + 15) / 16;    // 3125
    const int nbuck = (n + 127) >> 7;    // 391 buckets of 128 cols

    size_t npad    = ((size_t)n + 63) & ~(size_t)63;
    size_t o_deg   = 0;
    size_t o_ptr   = npad;                      // n+1 (+pad)
    size_t o_csr   = o_ptr + npad + 64;         // E ints
    size_t o_dinv  = o_csr + (size_t)E;
    size_t o_atab  = o_dinv + npad;             // n*64 fp16 = n*32 floats
    size_t o_btab  = o_atab + (size_t)n * 32;   // n*64 fp16
    size_t o_agg   = o_btab + (size_t)n * 32;   // n*32 fp32
    size_t o_xh    = o_agg + (size_t)n * 32;    // n*32 fp16 = n*16 floats
    size_t o_h2h   = o_xh + (size_t)n * 16;     // n*16 fp16 = n*8 floats
    size_t o_stage = o_h2h + (size_t)n * 8;     // E int2 (8B aligned: offsets even)
    size_t o_bcur  = o_stage + (size_t)E * 2;   // nbuck ints
    size_t o_part  = o_bcur + 512;              // 64 ints

    int*      deg    = (int*)(ws + o_deg);
    int*      ptr    = (int*)(ws + o_ptr);
    int*      csr    = (int*)(ws + o_csr);
    float*    dinv   = ws + o_dinv;
    _Float16* atab   = (_Float16*)(ws + o_atab);
    _Float16* btab   = (_Float16*)(ws + o_btab);
    float*    agg    = ws + o_agg;
    _Float16* xh     = (_Float16*)(ws + o_xh);
    _Float16* h2h    = (_Float16*)(ws + o_h2h);
    int2*     stage  = (int2*)(ws + o_stage);
    int*      bcur   = (int*)(ws + o_bcur);
    int*      part   = (int*)(ws + o_part);

    int nblk = (n + 3) / 4;                      // wave-per-node kernels, 4 waves/block
    int scan_nb = (n + SCAN_CHUNK - 1) / SCAN_CHUNK;   // 25 <= 64
    int fill_nb = (E + FILL_CH - 1) / FILL_CH;         // 196
    int m4 = n * 8;                                    // x float4 count

    hipMemsetAsync(deg, 0, npad * sizeof(int), stream);
    k_deg_cast<<<(E + 255) / 256, 256, 0, stream>>>(col, deg, (const float4*)x,
                                                    (f16x4*)xh, E, m4);
    k_scan_partial<<<scan_nb, 256, 0, stream>>>(deg, part, n);
    k_scan_final<<<scan_nb, 256, 0, stream>>>(deg, part, ptr, bcur, dinv, n, scan_nb, E);
    k_fill_a<<<fill_nb, 256, 0, stream>>>(row, col, bcur, stage, E, nbuck);
    k_fill_b<<<nbuck, 256, 0, stream>>>(ptr, stage, csr, n);
    k_gather32<<<nblk, 256, 0, stream>>>(ptr, csr, x, xh, dinv, agg, n);
    k_h1tab<<<256, 256, 0, stream>>>(agg, g1w, g1b, ew1, eb1, atab, btab, ntiles);
    k_edge_mlp<<<2048, 256, 0, stream>>>(ptr, csr, atab, btab, ew2, eb2, g2w, h2h, n);
    k_gcn2_gather<<<nblk, 256, 0, stream>>>(ptr, csr, h2h, dinv, g2b, out, n);
}